// Round 1
// baseline (534.427 us; speedup 1.0000x reference)
//
#include <hip/hip_runtime.h>
#include <hip/hip_bf16.h>
#include <stdint.h>

#define P_CNT 512
#define R_CNT 49
#define FEAT  2048
#define FDIM  200
#define DDIM  64
#define KC    128
#define NCHUNK (FEAT / KC)
#define LOG2E 1.44269504f

typedef __bf16 bf16;
typedef bf16  bf16x8 __attribute__((ext_vector_type(8)));
typedef float f32x4  __attribute__((ext_vector_type(4)));

// ws layout (byte offsets)
#define WS_U0    0        // 64 f32
#define WS_UI0   256      // 64 f32
#define WS_LIT   512      // 512 f32
#define WS_WCT   4096     // 64x2048 bf16 = 256 KB
#define WS_ALLX  266240   // 512x2048 f32 = 4 MB

__device__ __forceinline__ void gl_lds16(const void* g, void* l) {
  auto gp = reinterpret_cast<const uint32_t __attribute__((address_space(1)))*>(
      reinterpret_cast<uintptr_t>(g));
  auto lp = reinterpret_cast<uint32_t __attribute__((address_space(3)))*>(
      reinterpret_cast<uintptr_t>(l));
  __builtin_amdgcn_global_load_lds(gp, lp, 16, 0, 0);
}

// ---------------- K1: u0, ui0, output copies ----------------
__global__ __launch_bounds__(256) void k_prep(
    const float* __restrict__ Gu, const float* __restrict__ Gi, const float* __restrict__ Pi,
    const float* __restrict__ Wc0u, const float* __restrict__ bc0,
    const float* __restrict__ Wi0u, const float* __restrict__ bi0,
    const int* __restrict__ user, const int* __restrict__ item,
    float* __restrict__ out, float* __restrict__ ws)
{
  __shared__ float red[2][4][64];
  int tid = threadIdx.x;
  int d = tid & 63, q = tid >> 6;
  int us = user[0], it = item[0];
  const float* gu = Gu + (size_t)us * FDIM;
  float s0 = 0.f, s1 = 0.f;
  for (int f = q * 50; f < q * 50 + 50; ++f) {
    float g = gu[f];
    s0 += g * Wc0u[f * 64 + d];
    s1 += g * Wi0u[f * 64 + d];
  }
  red[0][q][d] = s0;
  red[1][q][d] = s1;
  __syncthreads();
  if (tid < 64) {
    ws[WS_U0 / 4 + tid] = red[0][0][tid] + red[0][1][tid] + red[0][2][tid] + red[0][3][tid] + bc0[tid];
  } else if (tid < 128) {
    int dd = tid - 64;
    ws[WS_UI0 / 4 + dd] = red[1][0][dd] + red[1][1][dd] + red[1][2][dd] + red[1][3][dd] + bi0[dd];
  }
  for (int i = tid; i < FDIM; i += 256) {
    out[1 + i]   = gu[i];
    out[201 + i] = Gi[(size_t)it * FDIM + i];
    out[401 + i] = Pi[(size_t)it * FDIM + i];
  }
}

// ---------------- K1b: Wc0_i -> bf16 transposed [64][2048] ----------------
__global__ __launch_bounds__(256) void k_wt(const float* __restrict__ Wci, bf16* __restrict__ wct)
{
  int g = blockIdx.x * 256 + threadIdx.x;  // 0..16383
  int d = g >> 8;                          // 0..63
  int c0 = (g & 255) * 8;
  bf16 tmp[8];
#pragma unroll
  for (int i = 0; i < 8; ++i) tmp[i] = (bf16)Wci[(size_t)(c0 + i) * 64 + d];
  *(bf16x8*)(wct + (size_t)d * FEAT + c0) = *(bf16x8*)tmp;
}

// ---------------- K2: per-p component attention ----------------
__global__ __launch_bounds__(256) void k_main(
    const float* __restrict__ f, const bf16* __restrict__ wct,
    const float* __restrict__ ws_u0, const float* __restrict__ Wc1,
    float* __restrict__ allx)
{
  __shared__ __align__(16) float Af[64 * KC];   // 32 KB, swizzled
  __shared__ __align__(16) bf16  Wt[64 * KC];   // 16 KB, swizzled
  __shared__ float lg[64];

  const int tid  = threadIdx.x;
  const int wave = tid >> 6;
  const int lane = tid & 63;
  const int p    = blockIdx.x;

  const int cl = lane & 15;
  const int g4 = lane >> 4;

  float u0c[4], w1c[4];
#pragma unroll
  for (int n = 0; n < 4; ++n) {
    u0c[n] = ws_u0[n * 16 + cl];
    w1c[n] = Wc1[n * 16 + cl];
  }

  f32x4 acc[4];
#pragma unroll
  for (int n = 0; n < 4; ++n) acc[n] = (f32x4){0.f, 0.f, 0.f, 0.f};

  const char* fb  = (const char*)(f + (size_t)p * R_CNT * FEAT);
  const char* wb  = (const char*)wct;
  char* afb = (char*)Af;
  char* wtb = (char*)Wt;

  const int arow = wave * 16 + cl;        // A row this lane reads for frags
  const int asw  = (arow & 7) << 4;

  for (int kc = 0; kc < NCHUNK; ++kc) {
    const int kc0 = kc * KC;
    __syncthreads();  // previous chunk fully consumed
    // stage A: 64 rows x 128 f32, 32 issues of 1 KB; this wave does 8
#pragma unroll
    for (int ii = 0; ii < 8; ++ii) {
      int iss = wave * 8 + ii;
      int r   = 2 * iss + (lane >> 5);
      int rc  = r < R_CNT ? r : (R_CNT - 1);             // clamp (pad rows get dup data)
      int boff = ((lane & 31) * 16) ^ ((r & 7) << 4);    // inverse-swizzled source
      gl_lds16(fb + (size_t)rc * (FEAT * 4) + kc0 * 4 + boff, afb + iss * 1024);
    }
    // stage W^T: 64 rows x 128 bf16, 16 issues of 1 KB; this wave does 4
#pragma unroll
    for (int ii = 0; ii < 4; ++ii) {
      int iss = wave * 4 + ii;
      int r   = 4 * iss + (lane >> 4);
      int boff = ((lane & 15) * 16) ^ ((r & 7) << 4);
      gl_lds16(wb + (size_t)r * (FEAT * 2) + kc0 * 2 + boff, wtb + iss * 1024);
    }
    __syncthreads();  // vmcnt(0) drained by barrier

#pragma unroll
    for (int ks = 0; ks < KC / 32; ++ks) {
      int kb = ks * 128 + g4 * 32;  // byte offset of this lane's 8 f32 k-slots
      const float4 a0 = *(const float4*)(afb + arow * (KC * 4) + ((kb)      ^ asw));
      const float4 a1 = *(const float4*)(afb + arow * (KC * 4) + ((kb + 16) ^ asw));
      bf16x8 afr;
      afr[0] = (bf16)a0.x; afr[1] = (bf16)a0.y; afr[2] = (bf16)a0.z; afr[3] = (bf16)a0.w;
      afr[4] = (bf16)a1.x; afr[5] = (bf16)a1.y; afr[6] = (bf16)a1.z; afr[7] = (bf16)a1.w;
      int kbb = ks * 64 + g4 * 16;  // bf16 bytes, same k_mine mapping as A
#pragma unroll
      for (int n = 0; n < 4; ++n) {
        int col = n * 16 + cl;
        bf16x8 bfr = *(const bf16x8*)(wtb + col * (KC * 2) + (kbb ^ ((col & 7) << 4)));
        acc[n] = __builtin_amdgcn_mfma_f32_16x16x32_bf16(afr, bfr, acc[n], 0, 0, 0);
      }
    }
  }

  // epilogue: logits[r] = sum_d relu(y + u0) * Wc1   (bc1 is softmax-invariant)
#pragma unroll
  for (int j = 0; j < 4; ++j) {
    float s = 0.f;
#pragma unroll
    for (int n = 0; n < 4; ++n) {
      float v = acc[n][j] + u0c[n];
      v = fmaxf(v, 0.f);
      s += v * w1c[n];
    }
    s += __shfl_xor(s, 1);
    s += __shfl_xor(s, 2);
    s += __shfl_xor(s, 4);
    s += __shfl_xor(s, 8);
    if (cl == 0) lg[wave * 16 + g4 * 4 + j] = s;
  }
  __syncthreads();

  // softmax over regions + weighted re-read (L3-resident)
  float m = -1e30f;
  for (int r = 0; r < R_CNT; ++r) m = fmaxf(m, lg[r]);
  float s = 0.f;
  for (int r = 0; r < R_CNT; ++r) s += exp2f((lg[r] - m) * LOG2E);
  float inv = 1.f / s;

  float a8[8];
#pragma unroll
  for (int i = 0; i < 8; ++i) a8[i] = 0.f;
  const float* fp = f + (size_t)p * R_CNT * FEAT + tid * 8;
  for (int r = 0; r < R_CNT; ++r) {
    float w = exp2f((lg[r] - m) * LOG2E);
    float4 x0 = *(const float4*)(fp + (size_t)r * FEAT);
    float4 x1 = *(const float4*)(fp + (size_t)r * FEAT + 4);
    a8[0] += w * x0.x; a8[1] += w * x0.y; a8[2] += w * x0.z; a8[3] += w * x0.w;
    a8[4] += w * x1.x; a8[5] += w * x1.y; a8[6] += w * x1.z; a8[7] += w * x1.w;
  }
  float* op = allx + (size_t)p * FEAT + tid * 8;
  float4 o0 = {a8[0] * inv, a8[1] * inv, a8[2] * inv, a8[3] * inv};
  float4 o1 = {a8[4] * inv, a8[5] * inv, a8[6] * inv, a8[7] * inv};
  *(float4*)op = o0;
  *(float4*)(op + 4) = o1;
}

// ---------------- K3: item-level logits (2 p per block) ----------------
__global__ __launch_bounds__(256) void k_item(
    const float* __restrict__ allx, const float* __restrict__ Gi, const float* __restrict__ Pi,
    const float* __restrict__ Wiv, const float* __restrict__ Wip, const float* __restrict__ Wix,
    const float* __restrict__ ws_ui0, const float* __restrict__ Wi1,
    const int* __restrict__ upos, float* __restrict__ lit)
{
  __shared__ __align__(16) float ax[2 * FEAT];  // 16 KB
  __shared__ float gp[2][FDIM];
  __shared__ float pp[2][FDIM];
  __shared__ float zr[4][2][64];
  int tid = threadIdx.x;
  int p0 = blockIdx.x * 2;

#pragma unroll
  for (int i = 0; i < 4; ++i) {
    int j = i * 256 + tid;  // float4 index into [2][2048]
    *(float4*)(ax + 4 * j) = *(const float4*)(allx + (size_t)p0 * FEAT + 4 * j);
  }
  int i0 = upos[p0], i1 = upos[p0 + 1];
  if (tid < FDIM) {
    gp[0][tid] = Gi[(size_t)i0 * FDIM + tid];
    gp[1][tid] = Gi[(size_t)i1 * FDIM + tid];
    pp[0][tid] = Pi[(size_t)i0 * FDIM + tid];
    pp[1][tid] = Pi[(size_t)i1 * FDIM + tid];
  }
  __syncthreads();

  int d = tid & 63, q = tid >> 6;
  float acc0 = 0.f, acc1 = 0.f;
  for (int c = q * 512; c < q * 512 + 512; c += 4) {
    float w0 = Wix[(size_t)(c + 0) * 64 + d];
    float w1 = Wix[(size_t)(c + 1) * 64 + d];
    float w2 = Wix[(size_t)(c + 2) * 64 + d];
    float w3 = Wix[(size_t)(c + 3) * 64 + d];
    float4 aa = *(const float4*)(ax + c);
    float4 bb = *(const float4*)(ax + FEAT + c);
    acc0 += aa.x * w0 + aa.y * w1 + aa.z * w2 + aa.w * w3;
    acc1 += bb.x * w0 + bb.y * w1 + bb.z * w2 + bb.w * w3;
  }
  for (int ff = q * 50; ff < q * 50 + 50; ++ff) {
    float wv = Wiv[(size_t)ff * 64 + d];
    float wp2 = Wip[(size_t)ff * 64 + d];
    acc0 += gp[0][ff] * wv + pp[0][ff] * wp2;
    acc1 += gp[1][ff] * wv + pp[1][ff] * wp2;
  }
  zr[q][0][d] = acc0;
  zr[q][1][d] = acc1;
  __syncthreads();
  if (tid < 128) {
    int pq = tid >> 6, dd = tid & 63;
    float z = zr[0][pq][dd] + zr[1][pq][dd] + zr[2][pq][dd] + zr[3][pq][dd] + ws_ui0[dd];
    z = fmaxf(z, 0.f);
    float t = z * Wi1[dd];  // bi1 is softmax-invariant
    t += __shfl_xor(t, 1);  t += __shfl_xor(t, 2);  t += __shfl_xor(t, 4);
    t += __shfl_xor(t, 8);  t += __shfl_xor(t, 16); t += __shfl_xor(t, 32);
    if (dd == 0) lit[p0 + pq] = t;
  }
}

// ---------------- K4: softmax over P, all_a, xui ----------------
__global__ __launch_bounds__(256) void k_fin(
    const float* __restrict__ lit, const int* __restrict__ upos,
    const float* __restrict__ Pi, const float* __restrict__ Gu, const float* __restrict__ Gi,
    const int* __restrict__ user, const int* __restrict__ item,
    float* __restrict__ out)
{
  __shared__ float la[512];
  __shared__ float red[4][FDIM];
  __shared__ float pr[256];
  __shared__ float wred[4];
  int tid = threadIdx.x;
  la[tid] = lit[tid];
  la[tid + 256] = lit[tid + 256];
  __syncthreads();
  float m = -1e30f;
  for (int i = 0; i < 512; ++i) m = fmaxf(m, la[i]);
  float s = 0.f;
  for (int i = 0; i < 512; ++i) s += exp2f((la[i] - m) * LOG2E);
  float inv = 1.f / s;

  int w = tid >> 6, lane = tid & 63;
  float a4[4] = {0.f, 0.f, 0.f, 0.f};
  for (int pi = 0; pi < 128; ++pi) {
    int pg = w * 128 + pi;
    float ap = exp2f((la[pg] - m) * LOG2E) * inv;
    const float* row = Pi + (size_t)upos[pg] * FDIM;
#pragma unroll
    for (int k = 0; k < 4; ++k) {
      int ff = lane + k * 64;
      if (ff < FDIM) a4[k] += ap * row[ff];
    }
  }
#pragma unroll
  for (int k = 0; k < 4; ++k) {
    int ff = lane + k * 64;
    if (ff < FDIM) red[w][ff] = a4[k];
  }
  pr[tid] = 0.f;
  __syncthreads();
  int us = user[0], it = item[0];
  if (tid < FDIM) {
    float alla = red[0][tid] + red[1][tid] + red[2][tid] + red[3][tid];
    float gup = Gu[(size_t)us * FDIM + tid] + alla;
    pr[tid] = gup * Gi[(size_t)it * FDIM + tid];
  }
  __syncthreads();
  float v = pr[tid];
  v += __shfl_xor(v, 1);  v += __shfl_xor(v, 2);  v += __shfl_xor(v, 4);
  v += __shfl_xor(v, 8);  v += __shfl_xor(v, 16); v += __shfl_xor(v, 32);
  if (lane == 0) wred[w] = v;
  __syncthreads();
  if (tid == 0) out[0] = wred[0] + wred[1] + wred[2] + wred[3];
}

extern "C" void kernel_launch(void* const* d_in, const int* in_sizes, int n_in,
                              void* d_out, int out_size, void* d_ws, size_t ws_size,
                              hipStream_t stream)
{
  const float* f    = (const float*)d_in[0];
  const float* Gu   = (const float*)d_in[1];
  const float* Gi   = (const float*)d_in[2];
  const float* Pi   = (const float*)d_in[3];
  const float* Wc0u = (const float*)d_in[4];
  const float* Wc0i = (const float*)d_in[5];
  const float* bc0  = (const float*)d_in[6];
  const float* Wc1  = (const float*)d_in[7];
  const float* Wi0u = (const float*)d_in[9];
  const float* Wiv  = (const float*)d_in[10];
  const float* Wip  = (const float*)d_in[11];
  const float* Wix  = (const float*)d_in[12];
  const float* bi0  = (const float*)d_in[13];
  const float* Wi1  = (const float*)d_in[14];
  const int* user   = (const int*)d_in[16];
  const int* item   = (const int*)d_in[17];
  const int* upos   = (const int*)d_in[18];

  float* out  = (float*)d_out;
  char*  ws   = (char*)d_ws;
  float* u0   = (float*)(ws + WS_U0);
  float* ui0  = (float*)(ws + WS_UI0);
  float* lit  = (float*)(ws + WS_LIT);
  bf16*  wct  = (bf16*)(ws + WS_WCT);
  float* allx = (float*)(ws + WS_ALLX);

  hipLaunchKernelGGL(k_prep, dim3(1),   dim3(256), 0, stream, Gu, Gi, Pi, Wc0u, bc0, Wi0u, bi0, user, item, out, (float*)ws);
  hipLaunchKernelGGL(k_wt,   dim3(64),  dim3(256), 0, stream, Wc0i, wct);
  hipLaunchKernelGGL(k_main, dim3(512), dim3(256), 0, stream, f, wct, u0, Wc1, allx);
  hipLaunchKernelGGL(k_item, dim3(256), dim3(256), 0, stream, allx, Gi, Pi, Wiv, Wip, Wix, ui0, Wi1, upos, lit);
  hipLaunchKernelGGL(k_fin,  dim3(1),   dim3(256), 0, stream, lit, upos, Pi, Gu, Gi, user, item, out);
}

// Round 4
// 478.554 us; speedup vs baseline: 1.1168x; 1.1168x over previous
//
#include <hip/hip_runtime.h>
#include <hip/hip_bf16.h>
#include <stdint.h>

#define P_CNT 512
#define R_CNT 49
#define FEAT  2048
#define FDIM  200
#define DDIM  64
#define KC2   64
#define NCH2  (FEAT / KC2)   // 32 chunks
#define MROWS (P_CNT * R_CNT) // 25088 flat rows
#define LOG2E 1.44269504f

typedef __bf16 bf16;
typedef bf16  bf16x8 __attribute__((ext_vector_type(8)));
typedef float f32x4  __attribute__((ext_vector_type(4)));

// ws layout (byte offsets)
#define WS_U0    0         // 64 f32
#define WS_UI0   256       // 64 f32
#define WS_LIT   512       // 512 f32 (item-level logits)
#define WS_LOG   4096      // 25088 f32 (component logits)
#define WS_PART  104448    // 32*200 f32 partials
#define WS_WCT   131072    // 64x2048 bf16 = 256 KB
#define WS_ALLX  393216    // 512x2048 f32 = 4 MB

__device__ __forceinline__ void gl_lds16(const void* g, void* l) {
  auto gp = reinterpret_cast<const uint32_t __attribute__((address_space(1)))*>(
      reinterpret_cast<uintptr_t>(g));
  auto lp = reinterpret_cast<uint32_t __attribute__((address_space(3)))*>(
      reinterpret_cast<uintptr_t>(l));
  __builtin_amdgcn_global_load_lds(gp, lp, 16, 0, 0);
}

// ---------------- K1: u0, ui0, output copies ----------------
__global__ __launch_bounds__(256) void k_prep(
    const float* __restrict__ Gu, const float* __restrict__ Gi, const float* __restrict__ Pi,
    const float* __restrict__ Wc0u, const float* __restrict__ bc0,
    const float* __restrict__ Wi0u, const float* __restrict__ bi0,
    const int* __restrict__ user, const int* __restrict__ item,
    float* __restrict__ out, float* __restrict__ ws)
{
  __shared__ float red[2][4][64];
  int tid = threadIdx.x;
  int d = tid & 63, q = tid >> 6;
  int us = user[0], it = item[0];
  const float* gu = Gu + (size_t)us * FDIM;
  float s0 = 0.f, s1 = 0.f;
#pragma unroll 5
  for (int f = q * 50; f < q * 50 + 50; ++f) {
    float g = gu[f];
    s0 += g * Wc0u[f * 64 + d];
    s1 += g * Wi0u[f * 64 + d];
  }
  red[0][q][d] = s0;
  red[1][q][d] = s1;
  __syncthreads();
  if (tid < 64) {
    ws[WS_U0 / 4 + tid] = red[0][0][tid] + red[0][1][tid] + red[0][2][tid] + red[0][3][tid] + bc0[tid];
  } else if (tid < 128) {
    int dd = tid - 64;
    ws[WS_UI0 / 4 + dd] = red[1][0][dd] + red[1][1][dd] + red[1][2][dd] + red[1][3][dd] + bi0[dd];
  }
  for (int i = tid; i < FDIM; i += 256) {
    out[1 + i]   = gu[i];
    out[201 + i] = Gi[(size_t)it * FDIM + i];
    out[401 + i] = Pi[(size_t)it * FDIM + i];
  }
}

// ---------------- K1b: Wc0_i [2048][64] -> bf16 transposed [64][2048] ----------------
__global__ __launch_bounds__(256) void k_wt(const float* __restrict__ Wci, bf16* __restrict__ wct)
{
  int g = blockIdx.x * 256 + threadIdx.x;  // 0..16383
  int d = g & 63;                          // lane-consecutive: coalesced reads
  int c0 = (g >> 6) * 8;
  bf16 tmp[8];
#pragma unroll
  for (int i = 0; i < 8; ++i) tmp[i] = (bf16)Wci[(size_t)(c0 + i) * 64 + d];
  *(bf16x8*)(wct + (size_t)d * FEAT + c0) = *(bf16x8*)tmp;
}

// ---------------- K2a: flat GEMM [25088 x 2048] @ [2048 x 64] -> logits ----------------
__global__ __launch_bounds__(256) void k_gemm(
    const float* __restrict__ f, const bf16* __restrict__ wct,
    const float* __restrict__ ws_u0, const float* __restrict__ Wc1,
    float* __restrict__ logits)
{
  __shared__ __align__(16) float Af[2][64 * KC2];  // 2 x 16 KB
  __shared__ __align__(16) bf16  Wt[2][64 * KC2];  // 2 x 8 KB

  const int tid  = threadIdx.x;
  const int wave = tid >> 6;
  const int lane = tid & 63;
  const int cl   = lane & 15;
  const int g4   = lane >> 4;

  const size_t row0 = (size_t)blockIdx.x * 64;
  const char* fb = (const char*)(f + row0 * FEAT);
  const char* wb = (const char*)wct;

  float u0c[4], w1c[4];
#pragma unroll
  for (int n = 0; n < 4; ++n) {
    u0c[n] = ws_u0[n * 16 + cl];
    w1c[n] = Wc1[n * 16 + cl];
  }
  f32x4 acc[4];
#pragma unroll
  for (int n = 0; n < 4; ++n) acc[n] = (f32x4){0.f, 0.f, 0.f, 0.f};

  const int arow = wave * 16 + cl;
  const int asw  = (arow & 7) << 4;

  auto STAGE = [&](int b, int kc) {
    const int kc0 = kc * KC2;
    char* afb = (char*)Af[b];
    char* wtb = (char*)Wt[b];
    // A: 64 rows x 256 B = 16 issues of 1 KB (4 rows each); this wave does 4
#pragma unroll
    for (int ii = 0; ii < 4; ++ii) {
      int iss = wave * 4 + ii;
      int r   = 4 * iss + (lane >> 4);
      int boff = ((lane & 15) * 16) ^ ((r & 7) << 4);  // inverse-swizzled source
      gl_lds16(fb + (size_t)r * (FEAT * 4) + kc0 * 4 + boff, afb + iss * 1024);
    }
    // W^T: 64 rows x 128 B = 8 issues of 1 KB (8 rows each); this wave does 2
#pragma unroll
    for (int ii = 0; ii < 2; ++ii) {
      int iss = wave * 2 + ii;
      int r   = 8 * iss + (lane >> 3);
      int boff = ((lane & 7) * 16) ^ ((r & 7) << 4);
      gl_lds16(wb + (size_t)r * (FEAT * 2) + kc0 * 2 + boff, wtb + iss * 1024);
    }
  };

  auto COMPUTE = [&](int b) {
    char* afb = (char*)Af[b];
    char* wtb = (char*)Wt[b];
#pragma unroll
    for (int ks = 0; ks < KC2 / 32; ++ks) {
      int kb = ks * 128 + g4 * 32;  // f32 byte offset of lane's 8 k-slots
      const float4 a0 = *(const float4*)(afb + arow * 256 + ((kb)      ^ asw));
      const float4 a1 = *(const float4*)(afb + arow * 256 + ((kb + 16) ^ asw));
      bf16x8 afr;
      afr[0] = (bf16)a0.x; afr[1] = (bf16)a0.y; afr[2] = (bf16)a0.z; afr[3] = (bf16)a0.w;
      afr[4] = (bf16)a1.x; afr[5] = (bf16)a1.y; afr[6] = (bf16)a1.z; afr[7] = (bf16)a1.w;
      int kbb = ks * 64 + g4 * 16;  // bf16 bytes
#pragma unroll
      for (int n = 0; n < 4; ++n) {
        int col = n * 16 + cl;
        bf16x8 bfr = *(const bf16x8*)(wtb + col * 128 + (kbb ^ ((col & 7) << 4)));
        acc[n] = __builtin_amdgcn_mfma_f32_16x16x32_bf16(afr, bfr, acc[n], 0, 0, 0);
      }
    }
  };

  STAGE(0, 0);
  __syncthreads();                 // buf0 ready (barrier drains vmcnt)
  int cur = 0;
  for (int kc = 0; kc < NCH2; ++kc) {
    if (kc + 1 < NCH2) STAGE(cur ^ 1, kc + 1);  // prefetch next chunk
    COMPUTE(cur);                               // overlap with in-flight loads
    __syncthreads();                            // drains vmcnt -> next buf ready
    cur ^= 1;
  }

  // logits[row] = sum_d relu(y + u0) * Wc1
#pragma unroll
  for (int j = 0; j < 4; ++j) {
    float s = 0.f;
#pragma unroll
    for (int n = 0; n < 4; ++n) {
      float v = acc[n][j] + u0c[n];
      v = fmaxf(v, 0.f);
      s += v * w1c[n];
    }
    s += __shfl_xor(s, 1);
    s += __shfl_xor(s, 2);
    s += __shfl_xor(s, 4);
    s += __shfl_xor(s, 8);
    if (cl == 0) logits[row0 + wave * 16 + g4 * 4 + j] = s;
  }
}

// ---------------- K2b: per-p softmax over regions + weighted sum ----------------
__global__ __launch_bounds__(256) void k_wsum(
    const float* __restrict__ f, const float* __restrict__ logits,
    float* __restrict__ allx)
{
  __shared__ float lg[R_CNT];
  const int tid = threadIdx.x;
  const int p   = blockIdx.x;
  if (tid < R_CNT) lg[tid] = logits[p * R_CNT + tid];
  __syncthreads();

  float m = -1e30f;
  for (int r = 0; r < R_CNT; ++r) m = fmaxf(m, lg[r]);
  float s = 0.f;
  for (int r = 0; r < R_CNT; ++r) s += exp2f((lg[r] - m) * LOG2E);
  float inv = 1.f / s;

  float a8[8];
#pragma unroll
  for (int i = 0; i < 8; ++i) a8[i] = 0.f;
  const float* fp = f + (size_t)p * R_CNT * FEAT + tid * 8;
  for (int r = 0; r < R_CNT; ++r) {
    float w = exp2f((lg[r] - m) * LOG2E);
    float4 x0 = *(const float4*)(fp + (size_t)r * FEAT);
    float4 x1 = *(const float4*)(fp + (size_t)r * FEAT + 4);
    a8[0] += w * x0.x; a8[1] += w * x0.y; a8[2] += w * x0.z; a8[3] += w * x0.w;
    a8[4] += w * x1.x; a8[5] += w * x1.y; a8[6] += w * x1.z; a8[7] += w * x1.w;
  }
  float* op = allx + (size_t)p * FEAT + tid * 8;
  float4 o0 = {a8[0] * inv, a8[1] * inv, a8[2] * inv, a8[3] * inv};
  float4 o1 = {a8[4] * inv, a8[5] * inv, a8[6] * inv, a8[7] * inv};
  *(float4*)op = o0;
  *(float4*)(op + 4) = o1;
}

// ---------------- K3: item-level logits (2 p per block) ----------------
__global__ __launch_bounds__(256) void k_item(
    const float* __restrict__ allx, const float* __restrict__ Gi, const float* __restrict__ Pi,
    const float* __restrict__ Wiv, const float* __restrict__ Wip, const float* __restrict__ Wix,
    const float* __restrict__ ws_ui0, const float* __restrict__ Wi1,
    const int* __restrict__ upos, float* __restrict__ lit)
{
  __shared__ __align__(16) float ax[2 * FEAT];  // 16 KB
  __shared__ float gp[2][FDIM];
  __shared__ float pp[2][FDIM];
  __shared__ float zr[4][2][64];
  int tid = threadIdx.x;
  int p0 = blockIdx.x * 2;

#pragma unroll
  for (int i = 0; i < 4; ++i) {
    int j = i * 256 + tid;
    *(float4*)(ax + 4 * j) = *(const float4*)(allx + (size_t)p0 * FEAT + 4 * j);
  }
  int i0 = upos[p0], i1 = upos[p0 + 1];
  if (tid < FDIM) {
    gp[0][tid] = Gi[(size_t)i0 * FDIM + tid];
    gp[1][tid] = Gi[(size_t)i1 * FDIM + tid];
    pp[0][tid] = Pi[(size_t)i0 * FDIM + tid];
    pp[1][tid] = Pi[(size_t)i1 * FDIM + tid];
  }
  __syncthreads();

  int d = tid & 63, q = tid >> 6;
  float acc0 = 0.f, acc1 = 0.f;
  for (int c = q * 512; c < q * 512 + 512; c += 4) {
    float w0 = Wix[(size_t)(c + 0) * 64 + d];
    float w1 = Wix[(size_t)(c + 1) * 64 + d];
    float w2 = Wix[(size_t)(c + 2) * 64 + d];
    float w3 = Wix[(size_t)(c + 3) * 64 + d];
    float4 aa = *(const float4*)(ax + c);
    float4 bb = *(const float4*)(ax + FEAT + c);
    acc0 += aa.x * w0 + aa.y * w1 + aa.z * w2 + aa.w * w3;
    acc1 += bb.x * w0 + bb.y * w1 + bb.z * w2 + bb.w * w3;
  }
  for (int ff = q * 50; ff < q * 50 + 50; ++ff) {
    float wv = Wiv[(size_t)ff * 64 + d];
    float wp2 = Wip[(size_t)ff * 64 + d];
    acc0 += gp[0][ff] * wv + pp[0][ff] * wp2;
    acc1 += gp[1][ff] * wv + pp[1][ff] * wp2;
  }
  zr[q][0][d] = acc0;
  zr[q][1][d] = acc1;
  __syncthreads();
  if (tid < 128) {
    int pq = tid >> 6, dd = tid & 63;
    float z = zr[0][pq][dd] + zr[1][pq][dd] + zr[2][pq][dd] + zr[3][pq][dd] + ws_ui0[dd];
    z = fmaxf(z, 0.f);
    float t = z * Wi1[dd];
    t += __shfl_xor(t, 1);  t += __shfl_xor(t, 2);  t += __shfl_xor(t, 4);
    t += __shfl_xor(t, 8);  t += __shfl_xor(t, 16); t += __shfl_xor(t, 32);
    if (dd == 0) lit[p0 + pq] = t;
  }
}

// ---------------- K4a: softmax over P + partial all_a (32 blocks x 16 p) ----------------
__global__ __launch_bounds__(256) void k_fina(
    const float* __restrict__ lit, const int* __restrict__ upos,
    const float* __restrict__ Pi, float* __restrict__ part)
{
  __shared__ float la[P_CNT];
  __shared__ float red[4][FDIM];
  int tid = threadIdx.x;
  la[tid] = lit[tid];
  la[tid + 256] = lit[tid + 256];
  __syncthreads();
  float m = -1e30f;
  for (int i = 0; i < P_CNT; ++i) m = fmaxf(m, la[i]);
  float s = 0.f;
  for (int i = 0; i < P_CNT; ++i) s += exp2f((la[i] - m) * LOG2E);
  float inv = 1.f / s;

  int w = tid >> 6, lane = tid & 63;
  float a4[4] = {0.f, 0.f, 0.f, 0.f};
#pragma unroll
  for (int i = 0; i < 4; ++i) {
    int pg = blockIdx.x * 16 + w * 4 + i;
    float ap = exp2f((la[pg] - m) * LOG2E) * inv;
    const float* row = Pi + (size_t)upos[pg] * FDIM;
#pragma unroll
    for (int k = 0; k < 4; ++k) {
      int ff = lane + k * 64;
      if (ff < FDIM) a4[k] += ap * row[ff];
    }
  }
#pragma unroll
  for (int k = 0; k < 4; ++k) {
    int ff = lane + k * 64;
    if (ff < FDIM) red[w][ff] = a4[k];
  }
  __syncthreads();
  if (tid < FDIM)
    part[blockIdx.x * FDIM + tid] = red[0][tid] + red[1][tid] + red[2][tid] + red[3][tid];
}

// ---------------- K4b: reduce partials + xui ----------------
__global__ __launch_bounds__(256) void k_finb(
    const float* __restrict__ part, const float* __restrict__ Gu, const float* __restrict__ Gi,
    const int* __restrict__ user, const int* __restrict__ item,
    float* __restrict__ out)
{
  __shared__ float pr[256];
  __shared__ float wred[4];
  int tid = threadIdx.x;
  int us = user[0], it = item[0];
  float v = 0.f;
  if (tid < FDIM) {
    float alla = 0.f;
#pragma unroll
    for (int b = 0; b < 32; ++b) alla += part[b * FDIM + tid];
    float gup = Gu[(size_t)us * FDIM + tid] + alla;
    v = gup * Gi[(size_t)it * FDIM + tid];
  }
  pr[tid] = v;
  __syncthreads();
  v = pr[tid];
  v += __shfl_xor(v, 1);  v += __shfl_xor(v, 2);  v += __shfl_xor(v, 4);
  v += __shfl_xor(v, 8);  v += __shfl_xor(v, 16); v += __shfl_xor(v, 32);
  int w = tid >> 6;
  if ((tid & 63) == 0) wred[w] = v;
  __syncthreads();
  if (tid == 0) out[0] = wred[0] + wred[1] + wred[2] + wred[3];
}

extern "C" void kernel_launch(void* const* d_in, const int* in_sizes, int n_in,
                              void* d_out, int out_size, void* d_ws, size_t ws_size,
                              hipStream_t stream)
{
  const float* f    = (const float*)d_in[0];
  const float* Gu   = (const float*)d_in[1];
  const float* Gi   = (const float*)d_in[2];
  const float* Pi   = (const float*)d_in[3];
  const float* Wc0u = (const float*)d_in[4];
  const float* Wc0i = (const float*)d_in[5];
  const float* bc0  = (const float*)d_in[6];
  const float* Wc1  = (const float*)d_in[7];
  const float* Wi0u = (const float*)d_in[9];
  const float* Wiv  = (const float*)d_in[10];
  const float* Wip  = (const float*)d_in[11];
  const float* Wix  = (const float*)d_in[12];
  const float* bi0  = (const float*)d_in[13];
  const float* Wi1  = (const float*)d_in[14];
  const int* user   = (const int*)d_in[16];
  const int* item   = (const int*)d_in[17];
  const int* upos   = (const int*)d_in[18];

  float* out  = (float*)d_out;
  char*  ws   = (char*)d_ws;
  float* u0   = (float*)(ws + WS_U0);
  float* ui0  = (float*)(ws + WS_UI0);
  float* lit  = (float*)(ws + WS_LIT);
  float* logi = (float*)(ws + WS_LOG);
  float* part = (float*)(ws + WS_PART);
  bf16*  wct  = (bf16*)(ws + WS_WCT);
  float* allx = (float*)(ws + WS_ALLX);

  hipLaunchKernelGGL(k_prep, dim3(1),   dim3(256), 0, stream, Gu, Gi, Pi, Wc0u, bc0, Wi0u, bi0, user, item, out, (float*)ws);
  hipLaunchKernelGGL(k_wt,   dim3(64),  dim3(256), 0, stream, Wc0i, wct);
  hipLaunchKernelGGL(k_gemm, dim3(MROWS / 64), dim3(256), 0, stream, f, wct, u0, Wc1, logi);
  hipLaunchKernelGGL(k_wsum, dim3(P_CNT), dim3(256), 0, stream, f, logi, allx);
  hipLaunchKernelGGL(k_item, dim3(P_CNT / 2), dim3(256), 0, stream, allx, Gi, Pi, Wiv, Wip, Wix, ui0, Wi1, upos, lit);
  hipLaunchKernelGGL(k_fina, dim3(32),  dim3(256), 0, stream, lit, upos, Pi, part);
  hipLaunchKernelGGL(k_finb, dim3(1),   dim3(256), 0, stream, part, Gu, Gi, user, item, out);
}

// Round 6
// 432.751 us; speedup vs baseline: 1.2350x; 1.1058x over previous
//
#include <hip/hip_runtime.h>
#include <hip/hip_bf16.h>
#include <stdint.h>

#define P_CNT 512
#define R_CNT 49
#define FEAT  2048
#define FDIM  200
#define KC2   64
#define NCH2  (FEAT / KC2)   // 32 chunks
#define LOG2E 1.44269504f
#define AISS  13             // A-staging issues per chunk (49 rows x 256 B -> 13 KB)
#define ABUF  (AISS * 1024)

typedef __bf16 bf16;
typedef bf16  bf16x8 __attribute__((ext_vector_type(8)));
typedef float f32x4  __attribute__((ext_vector_type(4)));

// ws layout (byte offsets)
#define WS_U0    0         // 64 f32
#define WS_UI0   256       // 64 f32
#define WS_LIT   512       // 512 f32 (item-level logits)
#define WS_WCT   4096      // 64x2048 bf16 = 256 KB
#define WS_ALLX  266240    // 512x2048 f32 = 4 MB

__device__ __forceinline__ void gl_lds16(const void* g, void* l) {
  auto gp = reinterpret_cast<const uint32_t __attribute__((address_space(1)))*>(
      reinterpret_cast<uintptr_t>(g));
  auto lp = reinterpret_cast<uint32_t __attribute__((address_space(3)))*>(
      reinterpret_cast<uintptr_t>(l));
  __builtin_amdgcn_global_load_lds(gp, lp, 16, 0, 0);
}

// ---------------- K1: prep (u0, ui0, copies, xui base) + W-transpose ----------------
__global__ __launch_bounds__(256) void k_init(
    const float* __restrict__ Gu, const float* __restrict__ Gi, const float* __restrict__ Pi,
    const float* __restrict__ Wc0u, const float* __restrict__ bc0,
    const float* __restrict__ Wi0u, const float* __restrict__ bi0,
    const float* __restrict__ Wci,
    const int* __restrict__ user, const int* __restrict__ item,
    float* __restrict__ out, float* __restrict__ ws, bf16* __restrict__ wct)
{
  int tid = threadIdx.x;
  if (blockIdx.x == 0) {
    __shared__ float red[2][4][64];
    __shared__ float wred[4];
    int d = tid & 63, q = tid >> 6;
    int us = user[0], it = item[0];
    const float* gu = Gu + (size_t)us * FDIM;
    float s0 = 0.f, s1 = 0.f;
#pragma unroll 5
    for (int f2 = q * 50; f2 < q * 50 + 50; ++f2) {
      float g = gu[f2];
      s0 += g * Wc0u[f2 * 64 + d];
      s1 += g * Wi0u[f2 * 64 + d];
    }
    red[0][q][d] = s0;
    red[1][q][d] = s1;
    // xui base term: dot(g_u, gamma_i)
    float pv = (tid < FDIM) ? gu[tid] * Gi[(size_t)it * FDIM + tid] : 0.f;
    pv += __shfl_xor(pv, 1);  pv += __shfl_xor(pv, 2);  pv += __shfl_xor(pv, 4);
    pv += __shfl_xor(pv, 8);  pv += __shfl_xor(pv, 16); pv += __shfl_xor(pv, 32);
    if (d == 0) wred[q] = pv;
    __syncthreads();
    if (tid < 64) {
      ws[WS_U0 / 4 + tid] = red[0][0][tid] + red[0][1][tid] + red[0][2][tid] + red[0][3][tid] + bc0[tid];
    } else if (tid < 128) {
      int dd = tid - 64;
      ws[WS_UI0 / 4 + dd] = red[1][0][dd] + red[1][1][dd] + red[1][2][dd] + red[1][3][dd] + bi0[dd];
    } else if (tid == 128) {
      out[0] = wred[0] + wred[1] + wred[2] + wred[3];
    }
    for (int i = tid; i < FDIM; i += 256) {
      out[1 + i]   = gu[i];
      out[201 + i] = Gi[(size_t)it * FDIM + i];
      out[401 + i] = Pi[(size_t)it * FDIM + i];
    }
  } else {
    int g = (blockIdx.x - 1) * 256 + tid;  // 0..16383
    int d = g & 63;                        // lane-consecutive: coalesced reads
    int c0 = (g >> 6) * 8;
    bf16 tmp[8];
#pragma unroll
    for (int i = 0; i < 8; ++i) tmp[i] = (bf16)Wci[(size_t)(c0 + i) * 64 + d];
    *(bf16x8*)(wct + (size_t)d * FEAT + c0) = *(bf16x8*)tmp;
  }
}

// ---------------- K2: fused per-p component attention ----------------
// GEMM [49 x 2048] @ [2048 x 64] -> logits -> softmax(R) -> weighted f-sum -> allx[p]
__global__ __launch_bounds__(256) void k_comp(
    const float* __restrict__ f, const bf16* __restrict__ wct,
    const float* __restrict__ ws_u0, const float* __restrict__ Wc1,
    float* __restrict__ allx)
{
  __shared__ __align__(16) char AfB[2][ABUF];      // 2 x 13 KB (49 rows x 256 B)
  __shared__ __align__(16) bf16 Wt[2][64 * KC2];   // 2 x 8 KB
  __shared__ float lg[64];

  const int tid  = threadIdx.x;
  const int wave = tid >> 6;
  const int lane = tid & 63;
  const int cl   = lane & 15;
  const int g4   = lane >> 4;
  const int p    = blockIdx.x;

  const char* fb = (const char*)(f + (size_t)p * R_CNT * FEAT);
  const char* wb = (const char*)wct;

  float u0c[4], w1c[4];
#pragma unroll
  for (int n = 0; n < 4; ++n) {
    u0c[n] = ws_u0[n * 16 + cl];
    w1c[n] = Wc1[n * 16 + cl];
  }
  f32x4 acc[4];
#pragma unroll
  for (int n = 0; n < 4; ++n) acc[n] = (f32x4){0.f, 0.f, 0.f, 0.f};

  const int arow = wave * 16 + cl;       // rows >= 49 produce ignored logits
  const int asw  = (arow & 7) << 4;

  auto STAGE = [&](int b, int kc) {
    const int kc0 = kc * KC2;
    char* afb = AfB[b];
    char* wtb = (char*)Wt[b];
    // A: 49 rows x 256 B -> 13 issues of 1 KB (4 rows each); strided over waves
#pragma unroll
    for (int ii = 0; ii < 4; ++ii) {
      int iss = wave + 4 * ii;
      if (iss < AISS) {
        int r  = 4 * iss + (lane >> 4);
        int rs = r < R_CNT ? r : (R_CNT - 1);          // clamp src (L2-hit re-read)
        int boff = ((lane & 15) * 16) ^ ((r & 7) << 4); // inverse-swizzled source
        gl_lds16(fb + (size_t)rs * (FEAT * 4) + kc0 * 4 + boff, afb + iss * 1024);
      }
    }
    // W^T: 64 rows x 128 B -> 8 issues of 1 KB; this wave does 2
#pragma unroll
    for (int ii = 0; ii < 2; ++ii) {
      int iss = wave * 2 + ii;
      int r   = 8 * iss + (lane >> 3);
      int boff = ((lane & 7) * 16) ^ ((r & 7) << 4);
      gl_lds16(wb + (size_t)r * (FEAT * 2) + kc0 * 2 + boff, wtb + iss * 1024);
    }
  };

  auto COMPUTE = [&](int b) {
    char* afb = AfB[b];
    char* wtb = (char*)Wt[b];
#pragma unroll
    for (int ks = 0; ks < KC2 / 32; ++ks) {
      int kb = ks * 128 + g4 * 32;  // f32 byte offset of lane's 8 k-slots
      const float4 a0 = *(const float4*)(afb + arow * 256 + ((kb)      ^ asw));
      const float4 a1 = *(const float4*)(afb + arow * 256 + ((kb + 16) ^ asw));
      bf16x8 afr;
      afr[0] = (bf16)a0.x; afr[1] = (bf16)a0.y; afr[2] = (bf16)a0.z; afr[3] = (bf16)a0.w;
      afr[4] = (bf16)a1.x; afr[5] = (bf16)a1.y; afr[6] = (bf16)a1.z; afr[7] = (bf16)a1.w;
      int kbb = ks * 64 + g4 * 16;  // bf16 bytes
#pragma unroll
      for (int n = 0; n < 4; ++n) {
        int col = n * 16 + cl;
        bf16x8 bfr = *(const bf16x8*)(wtb + col * 128 + (kbb ^ ((col & 7) << 4)));
        acc[n] = __builtin_amdgcn_mfma_f32_16x16x32_bf16(afr, bfr, acc[n], 0, 0, 0);
      }
    }
  };

  STAGE(0, 0);
  __syncthreads();                 // buf0 ready (compiler drains vmcnt at barrier)
  int cur = 0;
  for (int kc = 0; kc < NCH2; ++kc) {
    if (kc + 1 < NCH2) STAGE(cur ^ 1, kc + 1);  // prefetch next chunk
    COMPUTE(cur);                               // overlaps with in-flight loads
    __syncthreads();
    cur ^= 1;
  }

  // logits[r] = sum_d relu(y + u0) * Wc1  (bc1 softmax-invariant)
#pragma unroll
  for (int j = 0; j < 4; ++j) {
    float s = 0.f;
#pragma unroll
    for (int n = 0; n < 4; ++n) {
      float v = acc[n][j] + u0c[n];
      v = fmaxf(v, 0.f);
      s += v * w1c[n];
    }
    s += __shfl_xor(s, 1);
    s += __shfl_xor(s, 2);
    s += __shfl_xor(s, 4);
    s += __shfl_xor(s, 8);
    if (cl == 0) lg[wave * 16 + g4 * 4 + j] = s;
  }
  __syncthreads();

  // softmax over 49 regions (broadcast LDS reads), weights folded with 1/sum
  float m = -1e30f;
  for (int r = 0; r < R_CNT; ++r) m = fmaxf(m, lg[r]);
  float s = 0.f;
  for (int r = 0; r < R_CNT; ++r) s += exp2f((lg[r] - m) * LOG2E);
  float inv = 1.f / s;
  __syncthreads();
  if (tid < R_CNT) lg[tid] = exp2f((lg[tid] - m) * LOG2E) * inv;
  __syncthreads();

  // weighted re-read of f rows (L3-resident) -> allx[p]
  float a8[8];
#pragma unroll
  for (int i = 0; i < 8; ++i) a8[i] = 0.f;
  const float* fp = f + (size_t)p * R_CNT * FEAT + tid * 8;
  for (int r = 0; r < R_CNT; ++r) {
    float w = lg[r];
    float4 x0 = *(const float4*)(fp + (size_t)r * FEAT);
    float4 x1 = *(const float4*)(fp + (size_t)r * FEAT + 4);
    a8[0] += w * x0.x; a8[1] += w * x0.y; a8[2] += w * x0.z; a8[3] += w * x0.w;
    a8[4] += w * x1.x; a8[5] += w * x1.y; a8[6] += w * x1.z; a8[7] += w * x1.w;
  }
  float* op = allx + (size_t)p * FEAT + tid * 8;
  float4 o0 = {a8[0], a8[1], a8[2], a8[3]};
  float4 o1 = {a8[4], a8[5], a8[6], a8[7]};
  *(float4*)op = o0;
  *(float4*)(op + 4) = o1;
}

// ---------------- K3: item-level logits (2 p per block) ----------------
__global__ __launch_bounds__(256) void k_item(
    const float* __restrict__ allx, const float* __restrict__ Gi, const float* __restrict__ Pi,
    const float* __restrict__ Wiv, const float* __restrict__ Wip, const float* __restrict__ Wix,
    const float* __restrict__ ws_ui0, const float* __restrict__ Wi1,
    const int* __restrict__ upos, float* __restrict__ lit)
{
  __shared__ __align__(16) float ax[2 * FEAT];  // 16 KB
  __shared__ float gp[2][FDIM];
  __shared__ float pp[2][FDIM];
  __shared__ float zr[4][2][64];
  int tid = threadIdx.x;
  int p0 = blockIdx.x * 2;

#pragma unroll
  for (int i = 0; i < 4; ++i) {
    int j = i * 256 + tid;
    *(float4*)(ax + 4 * j) = *(const float4*)(allx + (size_t)p0 * FEAT + 4 * j);
  }
  int i0 = upos[p0], i1 = upos[p0 + 1];
  if (tid < FDIM) {
    gp[0][tid] = Gi[(size_t)i0 * FDIM + tid];
    gp[1][tid] = Gi[(size_t)i1 * FDIM + tid];
    pp[0][tid] = Pi[(size_t)i0 * FDIM + tid];
    pp[1][tid] = Pi[(size_t)i1 * FDIM + tid];
  }
  __syncthreads();

  int d = tid & 63, q = tid >> 6;
  float acc0 = 0.f, acc1 = 0.f;
  for (int c = q * 512; c < q * 512 + 512; c += 4) {
    float w0 = Wix[(size_t)(c + 0) * 64 + d];
    float w1 = Wix[(size_t)(c + 1) * 64 + d];
    float w2 = Wix[(size_t)(c + 2) * 64 + d];
    float w3 = Wix[(size_t)(c + 3) * 64 + d];
    float4 aa = *(const float4*)(ax + c);
    float4 bb = *(const float4*)(ax + FEAT + c);
    acc0 += aa.x * w0 + aa.y * w1 + aa.z * w2 + aa.w * w3;
    acc1 += bb.x * w0 + bb.y * w1 + bb.z * w2 + bb.w * w3;
  }
  for (int ff = q * 50; ff < q * 50 + 50; ++ff) {
    float wv = Wiv[(size_t)ff * 64 + d];
    float wp2 = Wip[(size_t)ff * 64 + d];
    acc0 += gp[0][ff] * wv + pp[0][ff] * wp2;
    acc1 += gp[1][ff] * wv + pp[1][ff] * wp2;
  }
  zr[q][0][d] = acc0;
  zr[q][1][d] = acc1;
  __syncthreads();
  if (tid < 128) {
    int pq = tid >> 6, dd = tid & 63;
    float z = zr[0][pq][dd] + zr[1][pq][dd] + zr[2][pq][dd] + zr[3][pq][dd] + ws_ui0[dd];
    z = fmaxf(z, 0.f);
    float t = z * Wi1[dd];
    t += __shfl_xor(t, 1);  t += __shfl_xor(t, 2);  t += __shfl_xor(t, 4);
    t += __shfl_xor(t, 8);  t += __shfl_xor(t, 16); t += __shfl_xor(t, 32);
    if (dd == 0) lit[p0 + pq] = t;
  }
}

// ---------------- K4: softmax over P + xui contribution (atomicAdd) ----------------
__global__ __launch_bounds__(256) void k_fin(
    const float* __restrict__ lit, const int* __restrict__ upos,
    const float* __restrict__ Pi, const float* __restrict__ Gi,
    const int* __restrict__ item, float* __restrict__ out)
{
  __shared__ float la[P_CNT];
  __shared__ float rmax[4];
  __shared__ float rsum[4];
  __shared__ float rloc[4];
  int tid = threadIdx.x, w = tid >> 6, lane = tid & 63;
  float v0 = lit[tid], v1 = lit[tid + 256];
  la[tid] = v0;
  la[tid + 256] = v1;
  // wave-parallel max
  float mx = fmaxf(v0, v1);
  mx = fmaxf(mx, __shfl_xor(mx, 1));  mx = fmaxf(mx, __shfl_xor(mx, 2));
  mx = fmaxf(mx, __shfl_xor(mx, 4));  mx = fmaxf(mx, __shfl_xor(mx, 8));
  mx = fmaxf(mx, __shfl_xor(mx, 16)); mx = fmaxf(mx, __shfl_xor(mx, 32));
  if (lane == 0) rmax[w] = mx;
  __syncthreads();
  float m = fmaxf(fmaxf(rmax[0], rmax[1]), fmaxf(rmax[2], rmax[3]));
  float e = exp2f((v0 - m) * LOG2E) + exp2f((v1 - m) * LOG2E);
  e += __shfl_xor(e, 1);  e += __shfl_xor(e, 2);  e += __shfl_xor(e, 4);
  e += __shfl_xor(e, 8);  e += __shfl_xor(e, 16); e += __shfl_xor(e, 32);
  if (lane == 0) rsum[w] = e;
  __syncthreads();
  float inv = 1.f / (rsum[0] + rsum[1] + rsum[2] + rsum[3]);

  int it = item[0];
  const float* gamma = Gi + (size_t)it * FDIM;
  float g[4];
#pragma unroll
  for (int k = 0; k < 4; ++k) {
    int ff = lane + 64 * k;
    g[k] = (ff < FDIM) ? gamma[ff] : 0.f;
  }
  float local = 0.f;
#pragma unroll
  for (int i = 0; i < 4; ++i) {
    int pg = blockIdx.x * 16 + w * 4 + i;
    const float* row = Pi + (size_t)upos[pg] * FDIM;
    float d = 0.f;
#pragma unroll
    for (int k = 0; k < 4; ++k) {
      int ff = lane + 64 * k;
      if (ff < FDIM) d += row[ff] * g[k];
    }
    d += __shfl_xor(d, 1);  d += __shfl_xor(d, 2);  d += __shfl_xor(d, 4);
    d += __shfl_xor(d, 8);  d += __shfl_xor(d, 16); d += __shfl_xor(d, 32);
    float ap = exp2f((la[pg] - m) * LOG2E) * inv;
    local += ap * d;
  }
  if (lane == 0) rloc[w] = local;
  __syncthreads();
  if (tid == 0) atomicAdd(out, rloc[0] + rloc[1] + rloc[2] + rloc[3]);
}

extern "C" void kernel_launch(void* const* d_in, const int* in_sizes, int n_in,
                              void* d_out, int out_size, void* d_ws, size_t ws_size,
                              hipStream_t stream)
{
  const float* f    = (const float*)d_in[0];
  const float* Gu   = (const float*)d_in[1];
  const float* Gi   = (const float*)d_in[2];
  const float* Pi   = (const float*)d_in[3];
  const float* Wc0u = (const float*)d_in[4];
  const float* Wc0i = (const float*)d_in[5];
  const float* bc0  = (const float*)d_in[6];
  const float* Wc1  = (const float*)d_in[7];
  const float* Wi0u = (const float*)d_in[9];
  const float* Wiv  = (const float*)d_in[10];
  const float* Wip  = (const float*)d_in[11];
  const float* Wix  = (const float*)d_in[12];
  const float* bi0  = (const float*)d_in[13];
  const float* Wi1  = (const float*)d_in[14];
  const int* user   = (const int*)d_in[16];
  const int* item   = (const int*)d_in[17];
  const int* upos   = (const int*)d_in[18];

  float* out  = (float*)d_out;
  char*  ws   = (char*)d_ws;
  float* u0   = (float*)(ws + WS_U0);
  float* ui0  = (float*)(ws + WS_UI0);
  float* lit  = (float*)(ws + WS_LIT);
  bf16*  wct  = (bf16*)(ws + WS_WCT);
  float* allx = (float*)(ws + WS_ALLX);

  hipLaunchKernelGGL(k_init, dim3(65),    dim3(256), 0, stream,
                     Gu, Gi, Pi, Wc0u, bc0, Wi0u, bi0, Wc0i, user, item, out, (float*)ws, wct);
  hipLaunchKernelGGL(k_comp, dim3(P_CNT), dim3(256), 0, stream, f, wct, u0, Wc1, allx);
  hipLaunchKernelGGL(k_item, dim3(P_CNT / 2), dim3(256), 0, stream,
                     allx, Gi, Pi, Wiv, Wip, Wix, ui0, Wi1, upos, lit);
  hipLaunchKernelGGL(k_fin,  dim3(32),    dim3(256), 0, stream, lit, upos, Pi, Gi, item, out);
}

// Round 7
// 406.441 us; speedup vs baseline: 1.3149x; 1.0647x over previous
//
#include <hip/hip_runtime.h>
#include <hip/hip_bf16.h>
#include <stdint.h>

#define P_CNT 512
#define R_CNT 49
#define FEAT  2048
#define FDIM  200
#define KC2   64
#define NCH2  (FEAT / KC2)   // 32 chunks
#define LOG2E 1.44269504f
#define AISS  13             // A-staging issues per chunk (49 rows x 256 B)
#define ABUF  (AISS * 1024)
#define BISS  16             // B-staging issues per chunk (128 rows x 128 B)
#define BBUF  (BISS * 1024)

typedef __bf16 bf16;
typedef bf16  bf16x8 __attribute__((ext_vector_type(8)));
typedef float f32x4  __attribute__((ext_vector_type(4)));

// ws layout (byte offsets)
#define WS_U0    0         // 64 f32  (g_u@Wc0_u + bc0)
#define WS_UI0   256       // 64 f32  (g_u@Wi0_u + bi0)
#define WS_LIT   512       // 512 f32 (item-level logits)
#define WS_WCT   4096      // 128x2048 bf16 = 512 KB ([Wc0_i^T ; Wi0_ix^T])

__device__ __forceinline__ void gl_lds16(const void* g, void* l) {
  auto gp = reinterpret_cast<const uint32_t __attribute__((address_space(1)))*>(
      reinterpret_cast<uintptr_t>(g));
  auto lp = reinterpret_cast<uint32_t __attribute__((address_space(3)))*>(
      reinterpret_cast<uintptr_t>(l));
  __builtin_amdgcn_global_load_lds(gp, lp, 16, 0, 0);
}

// ---------------- K1: prep (u0, ui0, copies, xui base) + dual W-transpose ----------------
__global__ __launch_bounds__(256) void k_init(
    const float* __restrict__ Gu, const float* __restrict__ Gi, const float* __restrict__ Pi,
    const float* __restrict__ Wc0u, const float* __restrict__ bc0,
    const float* __restrict__ Wi0u, const float* __restrict__ bi0,
    const float* __restrict__ Wci, const float* __restrict__ Wix,
    const int* __restrict__ user, const int* __restrict__ item,
    float* __restrict__ out, float* __restrict__ ws, bf16* __restrict__ wct)
{
  int tid = threadIdx.x;
  if (blockIdx.x == 0) {
    __shared__ float red[2][4][64];
    __shared__ float wred[4];
    int d = tid & 63, q = tid >> 6;
    int us = user[0], it = item[0];
    const float* gu = Gu + (size_t)us * FDIM;
    float s0 = 0.f, s1 = 0.f;
#pragma unroll 5
    for (int f2 = q * 50; f2 < q * 50 + 50; ++f2) {
      float g = gu[f2];
      s0 += g * Wc0u[f2 * 64 + d];
      s1 += g * Wi0u[f2 * 64 + d];
    }
    red[0][q][d] = s0;
    red[1][q][d] = s1;
    // xui base term: dot(g_u, gamma_i)
    float pv = (tid < FDIM) ? gu[tid] * Gi[(size_t)it * FDIM + tid] : 0.f;
    pv += __shfl_xor(pv, 1);  pv += __shfl_xor(pv, 2);  pv += __shfl_xor(pv, 4);
    pv += __shfl_xor(pv, 8);  pv += __shfl_xor(pv, 16); pv += __shfl_xor(pv, 32);
    if (d == 0) wred[q] = pv;
    __syncthreads();
    if (tid < 64) {
      ws[WS_U0 / 4 + tid] = red[0][0][tid] + red[0][1][tid] + red[0][2][tid] + red[0][3][tid] + bc0[tid];
    } else if (tid < 128) {
      int dd = tid - 64;
      ws[WS_UI0 / 4 + dd] = red[1][0][dd] + red[1][1][dd] + red[1][2][dd] + red[1][3][dd] + bi0[dd];
    } else if (tid == 128) {
      out[0] = wred[0] + wred[1] + wred[2] + wred[3];
    }
    for (int i = tid; i < FDIM; i += 256) {
      out[1 + i]   = gu[i];
      out[201 + i] = Gi[(size_t)it * FDIM + i];
      out[401 + i] = Pi[(size_t)it * FDIM + i];
    }
  } else {
    int g = (blockIdx.x - 1) * 256 + tid;  // 0..32767
    int mat = g >> 14;                     // 0: Wc0_i, 1: Wi0_ix
    int d   = g & 63;                      // lane-consecutive: coalesced reads
    int c0  = ((g >> 6) & 255) * 8;
    const float* src = mat ? Wix : Wci;
    bf16 tmp[8];
#pragma unroll
    for (int i = 0; i < 8; ++i) tmp[i] = (bf16)src[(size_t)(c0 + i) * 64 + d];
    *(bf16x8*)(wct + (size_t)(mat * 64 + d) * FEAT + c0) = *(bf16x8*)tmp;
  }
}

// ---------------- K2: fused per-p component attention + item-level logit ----------------
// GEMM [49 x 2048] @ [2048 x 128] -> {logits (cols 0..63), y2 (cols 64..127)}
// -> softmax(R) -> xg = sum_r b_r * y2[r,:]  (no second pass over f!)
// -> z = ui0 + g_pos@Wiv + p_pos@Wip + xg -> relu -> dot Wi1 -> lit[p]
__global__ __launch_bounds__(256) void k_comp(
    const float* __restrict__ f, const bf16* __restrict__ wct,
    const float* __restrict__ ws_u0, const float* __restrict__ Wc1,
    const float* __restrict__ Gi, const float* __restrict__ Pi,
    const float* __restrict__ Wiv, const float* __restrict__ Wip,
    const float* __restrict__ ws_ui0, const float* __restrict__ Wi1,
    const int* __restrict__ upos, float* __restrict__ lit)
{
  __shared__ __align__(16) char AfB[2][ABUF];      // 2 x 13 KB (49 rows x 256 B)
  __shared__ __align__(16) bf16 Wt[2][128 * KC2];  // 2 x 16 KB
  __shared__ float lg[64];
  __shared__ float xred[16][65];                   // padded: no bank conflict
  __shared__ float xg[64];
  __shared__ float gpL[FDIM], ppL[FDIM];
  __shared__ float zr2[4][64];

  const int tid  = threadIdx.x;
  const int wave = tid >> 6;
  const int lane = tid & 63;
  const int cl   = lane & 15;
  const int g4   = lane >> 4;
  const int p    = blockIdx.x;

  const char* fb = (const char*)(f + (size_t)p * R_CNT * FEAT);
  const char* wb = (const char*)wct;

  // prefetch item-level gathers early (independent of GEMM)
  int ip = upos[p];
  for (int i = tid; i < FDIM; i += 256) {
    gpL[i] = Gi[(size_t)ip * FDIM + i];
    ppL[i] = Pi[(size_t)ip * FDIM + i];
  }

  float u0c[4], w1c[4];
#pragma unroll
  for (int n = 0; n < 4; ++n) {
    u0c[n] = ws_u0[n * 16 + cl];
    w1c[n] = Wc1[n * 16 + cl];
  }
  f32x4 acc[8];
#pragma unroll
  for (int n = 0; n < 8; ++n) acc[n] = (f32x4){0.f, 0.f, 0.f, 0.f};

  const int arow = wave * 16 + cl;       // rows >= 49: garbage (guarded below)
  const int asw  = (arow & 7) << 4;

  auto STAGE = [&](int b, int kc) {
    const int kc0 = kc * KC2;
    char* afb = AfB[b];
    char* wtb = (char*)Wt[b];
    // A: 49 rows x 256 B -> 13 issues of 1 KB (4 rows each); strided over waves
#pragma unroll
    for (int ii = 0; ii < 4; ++ii) {
      int iss = wave + 4 * ii;
      if (iss < AISS) {
        int r  = 4 * iss + (lane >> 4);
        int rs = r < R_CNT ? r : (R_CNT - 1);           // clamp src
        int boff = ((lane & 15) * 16) ^ ((r & 7) << 4); // inverse-swizzled source
        gl_lds16(fb + (size_t)rs * (FEAT * 4) + kc0 * 4 + boff, afb + iss * 1024);
      }
    }
    // W^T: 128 rows x 128 B -> 16 issues of 1 KB (8 rows each); this wave does 4
#pragma unroll
    for (int ii = 0; ii < 4; ++ii) {
      int iss = wave * 4 + ii;
      int r   = 8 * iss + (lane >> 3);
      int boff = ((lane & 7) * 16) ^ ((r & 7) << 4);
      gl_lds16(wb + (size_t)r * (FEAT * 2) + kc0 * 2 + boff, wtb + iss * 1024);
    }
  };

  auto COMPUTE = [&](int b) {
    char* afb = AfB[b];
    char* wtb = (char*)Wt[b];
#pragma unroll
    for (int ks = 0; ks < KC2 / 32; ++ks) {
      int kb = ks * 128 + g4 * 32;  // f32 byte offset of lane's 8 k-slots
      const float4 a0 = *(const float4*)(afb + arow * 256 + ((kb)      ^ asw));
      const float4 a1 = *(const float4*)(afb + arow * 256 + ((kb + 16) ^ asw));
      bf16x8 afr;
      afr[0] = (bf16)a0.x; afr[1] = (bf16)a0.y; afr[2] = (bf16)a0.z; afr[3] = (bf16)a0.w;
      afr[4] = (bf16)a1.x; afr[5] = (bf16)a1.y; afr[6] = (bf16)a1.z; afr[7] = (bf16)a1.w;
      int kbb = ks * 64 + g4 * 16;  // bf16 bytes
#pragma unroll
      for (int n = 0; n < 8; ++n) {
        int col = n * 16 + cl;
        bf16x8 bfr = *(const bf16x8*)(wtb + col * 128 + (kbb ^ ((col & 7) << 4)));
        acc[n] = __builtin_amdgcn_mfma_f32_16x16x32_bf16(afr, bfr, acc[n], 0, 0, 0);
      }
    }
  };

  STAGE(0, 0);
  __syncthreads();                 // buf0 ready (compiler drains vmcnt at barrier)
  int cur = 0;
  for (int kc = 0; kc < NCH2; ++kc) {
    if (kc + 1 < NCH2) STAGE(cur ^ 1, kc + 1);  // prefetch next chunk
    COMPUTE(cur);                               // overlaps with in-flight loads
    __syncthreads();
    cur ^= 1;
  }

  // component logits[r] = sum_d relu(y + u0) * Wc1  (bc1 softmax-invariant)
#pragma unroll
  for (int j = 0; j < 4; ++j) {
    float s = 0.f;
#pragma unroll
    for (int n = 0; n < 4; ++n) {
      float v = acc[n][j] + u0c[n];
      v = fmaxf(v, 0.f);
      s += v * w1c[n];
    }
    s += __shfl_xor(s, 1);
    s += __shfl_xor(s, 2);
    s += __shfl_xor(s, 4);
    s += __shfl_xor(s, 8);
    if (cl == 0) lg[wave * 16 + g4 * 4 + j] = s;
  }
  __syncthreads();

  // softmax over 49 regions (broadcast LDS reads)
  float m = -1e30f;
  for (int r = 0; r < R_CNT; ++r) m = fmaxf(m, lg[r]);
  float s = 0.f;
  for (int r = 0; r < R_CNT; ++r) s += exp2f((lg[r] - m) * LOG2E);
  float inv = 1.f / s;
  __syncthreads();
  if (tid < R_CNT)       lg[tid] = exp2f((lg[tid] - m) * LOG2E) * inv;
  else if (tid < 64)     lg[tid] = 0.f;   // garbage rows neutralized
  __syncthreads();

  // xg[col] = sum_r b_r * y2[r][col]; guard r>=49 (never-staged LDS may be NaN)
#pragma unroll
  for (int n2 = 0; n2 < 4; ++n2) {
    float s2 = 0.f;
#pragma unroll
    for (int j = 0; j < 4; ++j) {
      int row = wave * 16 + g4 * 4 + j;
      if (row < R_CNT) s2 += lg[row] * acc[4 + n2][j];
    }
    xred[wave * 4 + g4][n2 * 16 + cl] = s2;
  }
  __syncthreads();
  if (tid < 64) {
    float s2 = 0.f;
#pragma unroll
    for (int i = 0; i < 16; ++i) s2 += xred[i][tid];
    xg[tid] = s2;
  }
  __syncthreads();

  // item-level logit: z = ui0 + g_pos@Wiv + p_pos@Wip + xg -> relu -> dot Wi1
  int d = tid & 63, q = tid >> 6;
  float za = 0.f;
#pragma unroll 5
  for (int f2 = q * 50; f2 < q * 50 + 50; ++f2)
    za += gpL[f2] * Wiv[f2 * 64 + d] + ppL[f2] * Wip[f2 * 64 + d];
  zr2[q][d] = za;
  __syncthreads();
  if (tid < 64) {
    float z = zr2[0][tid] + zr2[1][tid] + zr2[2][tid] + zr2[3][tid]
            + ws_ui0[tid] + xg[tid];
    z = fmaxf(z, 0.f);
    float t = z * Wi1[tid];   // bi1 softmax-invariant
    t += __shfl_xor(t, 1);  t += __shfl_xor(t, 2);  t += __shfl_xor(t, 4);
    t += __shfl_xor(t, 8);  t += __shfl_xor(t, 16); t += __shfl_xor(t, 32);
    if (tid == 0) lit[p] = t;
  }
}

// ---------------- K3: softmax over P + xui contribution (atomicAdd) ----------------
__global__ __launch_bounds__(256) void k_fin(
    const float* __restrict__ lit, const int* __restrict__ upos,
    const float* __restrict__ Pi, const float* __restrict__ Gi,
    const int* __restrict__ item, float* __restrict__ out)
{
  __shared__ float la[P_CNT];
  __shared__ float rmax[4];
  __shared__ float rsum[4];
  __shared__ float rloc[4];
  int tid = threadIdx.x, w = tid >> 6, lane = tid & 63;
  float v0 = lit[tid], v1 = lit[tid + 256];
  la[tid] = v0;
  la[tid + 256] = v1;
  float mx = fmaxf(v0, v1);
  mx = fmaxf(mx, __shfl_xor(mx, 1));  mx = fmaxf(mx, __shfl_xor(mx, 2));
  mx = fmaxf(mx, __shfl_xor(mx, 4));  mx = fmaxf(mx, __shfl_xor(mx, 8));
  mx = fmaxf(mx, __shfl_xor(mx, 16)); mx = fmaxf(mx, __shfl_xor(mx, 32));
  if (lane == 0) rmax[w] = mx;
  __syncthreads();
  float m = fmaxf(fmaxf(rmax[0], rmax[1]), fmaxf(rmax[2], rmax[3]));
  float e = exp2f((v0 - m) * LOG2E) + exp2f((v1 - m) * LOG2E);
  e += __shfl_xor(e, 1);  e += __shfl_xor(e, 2);  e += __shfl_xor(e, 4);
  e += __shfl_xor(e, 8);  e += __shfl_xor(e, 16); e += __shfl_xor(e, 32);
  if (lane == 0) rsum[w] = e;
  __syncthreads();
  float inv = 1.f / (rsum[0] + rsum[1] + rsum[2] + rsum[3]);

  int it = item[0];
  const float* gamma = Gi + (size_t)it * FDIM;
  float g[4];
#pragma unroll
  for (int k = 0; k < 4; ++k) {
    int ff = lane + 64 * k;
    g[k] = (ff < FDIM) ? gamma[ff] : 0.f;
  }
  float local = 0.f;
#pragma unroll
  for (int i = 0; i < 4; ++i) {
    int pg = blockIdx.x * 16 + w * 4 + i;
    const float* row = Pi + (size_t)upos[pg] * FDIM;
    float d = 0.f;
#pragma unroll
    for (int k = 0; k < 4; ++k) {
      int ff = lane + 64 * k;
      if (ff < FDIM) d += row[ff] * g[k];
    }
    d += __shfl_xor(d, 1);  d += __shfl_xor(d, 2);  d += __shfl_xor(d, 4);
    d += __shfl_xor(d, 8);  d += __shfl_xor(d, 16); d += __shfl_xor(d, 32);
    float ap = exp2f((la[pg] - m) * LOG2E) * inv;
    local += ap * d;
  }
  if (lane == 0) rloc[w] = local;
  __syncthreads();
  if (tid == 0) atomicAdd(out, rloc[0] + rloc[1] + rloc[2] + rloc[3]);
}

extern "C" void kernel_launch(void* const* d_in, const int* in_sizes, int n_in,
                              void* d_out, int out_size, void* d_ws, size_t ws_size,
                              hipStream_t stream)
{
  const float* f    = (const float*)d_in[0];
  const float* Gu   = (const float*)d_in[1];
  const float* Gi   = (const float*)d_in[2];
  const float* Pi   = (const float*)d_in[3];
  const float* Wc0u = (const float*)d_in[4];
  const float* Wc0i = (const float*)d_in[5];
  const float* bc0  = (const float*)d_in[6];
  const float* Wc1  = (const float*)d_in[7];
  const float* Wi0u = (const float*)d_in[9];
  const float* Wiv  = (const float*)d_in[10];
  const float* Wip  = (const float*)d_in[11];
  const float* Wix  = (const float*)d_in[12];
  const float* bi0  = (const float*)d_in[13];
  const float* Wi1  = (const float*)d_in[14];
  const int* user   = (const int*)d_in[16];
  const int* item   = (const int*)d_in[17];
  const int* upos   = (const int*)d_in[18];

  float* out  = (float*)d_out;
  char*  ws   = (char*)d_ws;
  float* u0   = (float*)(ws + WS_U0);
  float* ui0  = (float*)(ws + WS_UI0);
  float* lit  = (float*)(ws + WS_LIT);
  bf16*  wct  = (bf16*)(ws + WS_WCT);

  hipLaunchKernelGGL(k_init, dim3(129),   dim3(256), 0, stream,
                     Gu, Gi, Pi, Wc0u, bc0, Wi0u, bi0, Wc0i, Wix, user, item, out, (float*)ws, wct);
  hipLaunchKernelGGL(k_comp, dim3(P_CNT), dim3(256), 0, stream,
                     f, wct, u0, Wc1, Gi, Pi, Wiv, Wip, ui0, Wi1, upos, lit);
  hipLaunchKernelGGL(k_fin,  dim3(32),    dim3(256), 0, stream, lit, upos, Pi, Gi, item, out);
}